// Round 2
// baseline (386.104 us; speedup 1.0000x reference)
//
#include <hip/hip_runtime.h>

// Inputs/outputs are fp32 (reference dtypes); comparison is bf16-grade
// (2% rel + 8*bf16_eps floor), so internal compute uses bf16 MFMA.
// ws layout (needs 64 MB):
//   [0,8M)    Qb   bf16 [B,H,S,DK]  (post-PE)
//   [8M,24M)  Kf   fp32 [B,H,S,DK]  (raw K, pre-smear)
//   [24M,32M) Kb   bf16 [B,H,S,DK]  (post EMA+PE)
//   [32M,40M) Vb   bf16 [B,H,S,DK]
//   [40M,48M) Ab   bf16 [B,S,D]     (attention out)
//   [48M,64M) Yp   fp32 [B,S,D]     (out-proj + residual, pre-LN)

#define LB __launch_bounds__(256)

typedef unsigned short u16;
typedef __attribute__((ext_vector_type(4))) unsigned short us4;
typedef __attribute__((ext_vector_type(8))) unsigned short us8;
typedef __attribute__((ext_vector_type(8))) __bf16 bf8;
typedef __attribute__((ext_vector_type(4))) float f4;

static __device__ __forceinline__ float bf2f(u16 h) {
  union { unsigned int u; float f; } c; c.u = ((unsigned int)h) << 16; return c.f;
}
static __device__ __forceinline__ u16 f2bf(float f) {
  union { float f; unsigned int u; } c; c.f = f;
  unsigned int u = c.u + 0x7FFFu + ((c.u >> 16) & 1u);
  return (u16)(u >> 16);
}
// pe[s, dk]: i = dk/2, freq = 10000^(-2i/64); even->sin, odd->cos
static __device__ __forceinline__ float pe_val(int s, int dk) {
  float fr = __expf((float)(dk & ~1) * (-9.210340371976184f / 64.0f));
  float ang = (float)s * fr;
  return (dk & 1) ? __cosf(ang) : __sinf(ang);
}

// ---------------- QKV projection GEMM ----------------
// out[m,n] = sum_d X[m,d] * W[n,d]; M=4096, N=1024, K=1024; z selects W/{Q,K,V}.
// 128x128 tile, BK=32, 4 waves each 64x64 (4x4 tiles of 16x16).
// fp32 global -> bf16 LDS conversion during staging.
__global__ LB void gemm_qkv(const float* __restrict__ X, const float* __restrict__ Wq,
                            const float* __restrict__ Wk, const float* __restrict__ Wv,
                            u16* __restrict__ Qb, float* __restrict__ Kf,
                            u16* __restrict__ Vb) {
  __shared__ u16 Als[128 * 40];  // rows padded to 80B (40 u16) for bank spread
  __shared__ u16 Bls[128 * 40];
  const int tid = threadIdx.x;
  const int w = tid >> 6, lane = tid & 63;
  const int l16 = lane & 15, quad = lane >> 4;
  const int wm = w & 1, wn = w >> 1;
  const int m0 = blockIdx.y * 128, n0 = blockIdx.x * 128;
  const int z = blockIdx.z;
  const float* Wp = (z == 0) ? Wq : ((z == 1) ? Wk : Wv);

  f4 acc[4][4];
#pragma unroll
  for (int a = 0; a < 4; a++)
#pragma unroll
    for (int b = 0; b < 4; b++) acc[a][b] = f4{0.f, 0.f, 0.f, 0.f};

  for (int kk = 0; kk < 1024; kk += 32) {
    __syncthreads();
#pragma unroll
    for (int it = 0; it < 4; it++) {
      int c = tid + it * 256;          // 1024 chunks of 4 floats
      int row = c >> 3, kc = c & 7;
      f4 va = *(const f4*)(X + (size_t)(m0 + row) * 1024 + kk + kc * 4);
      us4 pa = {f2bf(va[0]), f2bf(va[1]), f2bf(va[2]), f2bf(va[3])};
      *(us4*)(&Als[row * 40 + kc * 4]) = pa;
      f4 vb = *(const f4*)(Wp + (size_t)(n0 + row) * 1024 + kk + kc * 4);
      us4 pb = {f2bf(vb[0]), f2bf(vb[1]), f2bf(vb[2]), f2bf(vb[3])};
      *(us4*)(&Bls[row * 40 + kc * 4]) = pb;
    }
    __syncthreads();
    bf8 af[4], bfr[4];
#pragma unroll
    for (int mt = 0; mt < 4; mt++)
      af[mt] = __builtin_bit_cast(bf8, *(const us8*)(&Als[(wm * 64 + mt * 16 + l16) * 40 + quad * 8]));
#pragma unroll
    for (int nt = 0; nt < 4; nt++)
      bfr[nt] = __builtin_bit_cast(bf8, *(const us8*)(&Bls[(wn * 64 + nt * 16 + l16) * 40 + quad * 8]));
#pragma unroll
    for (int mt = 0; mt < 4; mt++)
#pragma unroll
      for (int nt = 0; nt < 4; nt++)
        acc[mt][nt] = __builtin_amdgcn_mfma_f32_16x16x32_bf16(af[mt], bfr[nt], acc[mt][nt], 0, 0, 0);
  }
#pragma unroll
  for (int mt = 0; mt < 4; mt++)
#pragma unroll
    for (int nt = 0; nt < 4; nt++)
#pragma unroll
      for (int r = 0; r < 4; r++) {
        int m = m0 + wm * 64 + mt * 16 + quad * 4 + r;  // C/D: row = quad*4+r
        int n = n0 + wn * 64 + nt * 16 + l16;           //      col = lane&15
        float v = acc[mt][nt][r];
        int b = m >> 11, s = m & 2047, h = n >> 6, dk = n & 63;
        size_t o = (((size_t)(b * 16 + h)) * 2048 + s) * 64 + dk;  // [B,H,S,DK]
        if (z == 0)      Qb[o] = f2bf(v + pe_val(s, dk));  // Q gets PE fused
        else if (z == 1) Kf[o] = v;                        // raw K (fp32, pre-smear)
        else             Vb[o] = f2bf(v);
      }
}

// ---------------- EMA smear + PE on K ----------------
__global__ LB void ema_pe(const float* __restrict__ Kf, const float* __restrict__ alpha,
                          u16* __restrict__ Kb) {
  int idx = blockIdx.x * 256 + threadIdx.x;  // 1M threads, 4 elems each
  int dk4 = (idx & 15) * 4;
  int s   = (idx >> 4) & 2047;
  int bh  = idx >> 15;
  size_t base = ((size_t)bh * 2048 + s) * 64 + dk4;
  f4 kc = *(const f4*)(Kf + base);
  f4 kv = kc;
  if (s > 0) {
    f4 kp = *(const f4*)(Kf + base - 64);
    float aa = alpha[(bh & 15) * 2047 + s - 1];  // alpha[1,H,S-1,1]
    float a = 1.0f / (1.0f + __expf(-aa));
#pragma unroll
    for (int j = 0; j < 4; j++) kv[j] = kc[j] * a + kp[j] * (1.0f - a);
  }
#pragma unroll
  for (int j = 0; j < 4; j++) Kb[base + j] = f2bf(kv[j] + pe_val(s, dk4 + j));
}

// ---------------- causal flash attention ----------------
// block: (b,h) x 64 q-rows; 4 waves x 16 rows; 32-key steps.
__global__ LB void attn_kernel(const u16* __restrict__ Qb, const u16* __restrict__ Kb,
                               const u16* __restrict__ Vb, u16* __restrict__ Ab) {
  __shared__ u16 Vt[64 * 32];       // [d][key] transposed V tile
  __shared__ u16 Pls[4][16 * 32];   // per-wave P [q][key]
  const int tid = threadIdx.x, w = tid >> 6, lane = tid & 63;
  const int l16 = lane & 15, quad = lane >> 4;
  const int q0 = blockIdx.x * 64, bh = blockIdx.y;
  const size_t base = (size_t)bh * 2048 * 64;

  bf8 qa[2];
  {
    const int qrow = q0 + w * 16 + l16;
#pragma unroll
    for (int c = 0; c < 2; c++)
      qa[c] = __builtin_bit_cast(bf8, *(const us8*)(Qb + base + (size_t)qrow * 64 + c * 32 + quad * 8));
  }
  f4 acc[4];
#pragma unroll
  for (int dn = 0; dn < 4; dn++) acc[dn] = f4{0.f, 0.f, 0.f, 0.f};
  float mrow[4], lrow[4];
#pragma unroll
  for (int r = 0; r < 4; r++) { mrow[r] = -1e30f; lrow[r] = 0.f; }

  const int kend = q0 + 64;
  for (int kt = 0; kt < kend; kt += 32) {
    __syncthreads();  // protect Vt/Pls from previous iteration's readers
    {   // stage V[kt..kt+32) transposed: Vt[d][key]
      int key = tid & 31, db = tid >> 5;
      us8 v = *(const us8*)(Vb + base + (size_t)(kt + key) * 64 + db * 8);
#pragma unroll
      for (int j = 0; j < 8; j++) Vt[(db * 8 + j) * 32 + key] = v[j];
    }
    // scores: S[q, kt+16t+l16] for t=0,1 (K frags straight from global; L1-served)
    f4 sc[2];
    sc[0] = f4{0.f, 0.f, 0.f, 0.f}; sc[1] = f4{0.f, 0.f, 0.f, 0.f};
#pragma unroll
    for (int t = 0; t < 2; t++)
#pragma unroll
      for (int c = 0; c < 2; c++) {
        bf8 kb = __builtin_bit_cast(bf8, *(const us8*)(Kb + base + (size_t)(kt + 16 * t + l16) * 64 + c * 32 + quad * 8));
        sc[t] = __builtin_amdgcn_mfma_f32_16x16x32_bf16(qa[c], kb, sc[t], 0, 0, 0);
      }
    const int qg = q0 + w * 16 + quad * 4;
#pragma unroll
    for (int r = 0; r < 4; r++) {
      float s0 = sc[0][r] * 0.125f;
      float s1 = sc[1][r] * 0.125f;
      if (kt + l16      > qg + r) s0 = -1e30f;   // causal mask
      if (kt + 16 + l16 > qg + r) s1 = -1e30f;
      float mx = fmaxf(s0, s1);
#pragma unroll
      for (int d = 1; d < 16; d <<= 1) mx = fmaxf(mx, __shfl_xor(mx, d, 64));
      float mn = fmaxf(mrow[r], mx);
      float al = __expf(mrow[r] - mn);
      float p0 = __expf(s0 - mn), p1 = __expf(s1 - mn);
      float ps = p0 + p1;
#pragma unroll
      for (int d = 1; d < 16; d <<= 1) ps += __shfl_xor(ps, d, 64);
      lrow[r] = lrow[r] * al + ps;
      mrow[r] = mn;
#pragma unroll
      for (int dn = 0; dn < 4; dn++) acc[dn][r] *= al;
      Pls[w][(quad * 4 + r) * 32 + l16]      = f2bf(p0);
      Pls[w][(quad * 4 + r) * 32 + 16 + l16] = f2bf(p1);
    }
    __syncthreads();  // Vt staged + P visible
    // PV: A = P (A-layout via LDS round-trip), B = V from Vt
    bf8 pa = __builtin_bit_cast(bf8, *(const us8*)(&Pls[w][l16 * 32 + quad * 8]));
#pragma unroll
    for (int dn = 0; dn < 4; dn++) {
      bf8 vb = __builtin_bit_cast(bf8, *(const us8*)(&Vt[(dn * 16 + l16) * 32 + quad * 8]));
      acc[dn] = __builtin_amdgcn_mfma_f32_16x16x32_bf16(pa, vb, acc[dn], 0, 0, 0);
    }
  }
  const int b = bh >> 4, h = bh & 15;
#pragma unroll
  for (int dn = 0; dn < 4; dn++)
#pragma unroll
    for (int r = 0; r < 4; r++) {
      int q = q0 + w * 16 + quad * 4 + r;
      float v = acc[dn][r] / lrow[r];
      Ab[((size_t)(b * 2048 + q)) * 1024 + h * 64 + dn * 16 + l16] = f2bf(v);  // [B,S,D]
    }
}

// ---------------- output projection + residual ----------------
// A (attn out) is bf16 in ws; Wo/X fp32 from inputs; Yp fp32.
__global__ LB void gemm_out(const u16* __restrict__ A, const float* __restrict__ Wo,
                            const float* __restrict__ X, float* __restrict__ Yp) {
  __shared__ u16 Als[128 * 40];
  __shared__ u16 Bls[128 * 40];
  const int tid = threadIdx.x;
  const int w = tid >> 6, lane = tid & 63;
  const int l16 = lane & 15, quad = lane >> 4;
  const int wm = w & 1, wn = w >> 1;
  const int m0 = blockIdx.y * 128, n0 = blockIdx.x * 128;

  f4 acc[4][4];
#pragma unroll
  for (int a = 0; a < 4; a++)
#pragma unroll
    for (int b = 0; b < 4; b++) acc[a][b] = f4{0.f, 0.f, 0.f, 0.f};

  for (int kk = 0; kk < 1024; kk += 32) {
    __syncthreads();
#pragma unroll
    for (int it = 0; it < 2; it++) {   // A: bf16, 8-elem chunks
      int c = tid + it * 256;
      int row = c >> 2, kc = c & 3;
      us8 va = *(const us8*)(A + (size_t)(m0 + row) * 1024 + kk + kc * 8);
      *(us8*)(&Als[row * 40 + kc * 8]) = va;
    }
#pragma unroll
    for (int it = 0; it < 4; it++) {   // Wo: fp32, 4-elem chunks + convert
      int c = tid + it * 256;
      int row = c >> 3, kc = c & 7;
      f4 vb = *(const f4*)(Wo + (size_t)(n0 + row) * 1024 + kk + kc * 4);
      us4 pb = {f2bf(vb[0]), f2bf(vb[1]), f2bf(vb[2]), f2bf(vb[3])};
      *(us4*)(&Bls[row * 40 + kc * 4]) = pb;
    }
    __syncthreads();
    bf8 af[4], bfr[4];
#pragma unroll
    for (int mt = 0; mt < 4; mt++)
      af[mt] = __builtin_bit_cast(bf8, *(const us8*)(&Als[(wm * 64 + mt * 16 + l16) * 40 + quad * 8]));
#pragma unroll
    for (int nt = 0; nt < 4; nt++)
      bfr[nt] = __builtin_bit_cast(bf8, *(const us8*)(&Bls[(wn * 64 + nt * 16 + l16) * 40 + quad * 8]));
#pragma unroll
    for (int mt = 0; mt < 4; mt++)
#pragma unroll
      for (int nt = 0; nt < 4; nt++)
        acc[mt][nt] = __builtin_amdgcn_mfma_f32_16x16x32_bf16(af[mt], bfr[nt], acc[mt][nt], 0, 0, 0);
  }
#pragma unroll
  for (int mt = 0; mt < 4; mt++)
#pragma unroll
    for (int nt = 0; nt < 4; nt++)
#pragma unroll
      for (int r = 0; r < 4; r++) {
        int m = m0 + wm * 64 + mt * 16 + quad * 4 + r;
        int n = n0 + wn * 64 + nt * 16 + l16;
        size_t o = (size_t)m * 1024 + n;
        Yp[o] = acc[mt][nt][r] + X[o];  // residual (fp32)
      }
}

// ---------------- LayerNorm ----------------
__global__ LB void ln_kernel(const float* __restrict__ Y, const float* __restrict__ g,
                             const float* __restrict__ bta, float* __restrict__ out) {
  __shared__ float ls[4], lsq[4];
  const int row = blockIdx.x, tid = threadIdx.x;
  const int w = tid >> 6, lane = tid & 63;
  f4 v = *(const f4*)(Y + (size_t)row * 1024 + tid * 4);
  float s  = v[0] + v[1] + v[2] + v[3];
  float sq = v[0] * v[0] + v[1] * v[1] + v[2] * v[2] + v[3] * v[3];
#pragma unroll
  for (int d = 1; d < 64; d <<= 1) { s += __shfl_xor(s, d, 64); sq += __shfl_xor(sq, d, 64); }
  if (lane == 0) { ls[w] = s; lsq[w] = sq; }
  __syncthreads();
  s  = ls[0] + ls[1] + ls[2] + ls[3];
  sq = lsq[0] + lsq[1] + lsq[2] + lsq[3];
  float mu  = s * (1.0f / 1024.0f);
  float var = sq * (1.0f / 1024.0f) - mu * mu;
  float rs  = rsqrtf(var + 1e-5f);
  f4 o;
#pragma unroll
  for (int j = 0; j < 4; j++) {
    int col = tid * 4 + j;
    o[j] = (v[j] - mu) * rs * g[col] + bta[col];
  }
  *(f4*)(out + (size_t)row * 1024 + tid * 4) = o;
}

extern "C" void kernel_launch(void* const* d_in, const int* in_sizes, int n_in,
                              void* d_out, int out_size, void* d_ws, size_t ws_size,
                              hipStream_t stream) {
  (void)in_sizes; (void)n_in; (void)out_size; (void)ws_size;
  const float* X  = (const float*)d_in[0];
  const float* Wq = (const float*)d_in[1];
  const float* Wk = (const float*)d_in[2];
  const float* Wv = (const float*)d_in[3];
  const float* Wo = (const float*)d_in[4];
  const float* al = (const float*)d_in[5];
  const float* g  = (const float*)d_in[6];
  const float* bt = (const float*)d_in[7];

  char* ws = (char*)d_ws;
  u16*   Qb = (u16*)(ws);
  float* Kf = (float*)(ws + ((size_t)8  << 20));
  u16*   Kb = (u16*)(ws + ((size_t)24 << 20));
  u16*   Vb = (u16*)(ws + ((size_t)32 << 20));
  u16*   Ab = (u16*)(ws + ((size_t)40 << 20));
  float* Yp = (float*)(ws + ((size_t)48 << 20));

  gemm_qkv<<<dim3(8, 32, 3), 256, 0, stream>>>(X, Wq, Wk, Wv, Qb, Kf, Vb);
  ema_pe<<<dim3(4096), 256, 0, stream>>>(Kf, al, Kb);
  attn_kernel<<<dim3(32, 32), 256, 0, stream>>>(Qb, Kb, Vb, Ab);
  gemm_out<<<dim3(8, 32), 256, 0, stream>>>(Ab, Wo, X, Yp);
  ln_kernel<<<dim3(4096), 256, 0, stream>>>(Yp, g, bt, (float*)d_out);
}

// Round 3
// 325.898 us; speedup vs baseline: 1.1847x; 1.1847x over previous
//
#include <hip/hip_runtime.h>

// Inputs/outputs fp32 (reference dtypes); internal compute bf16 MFMA
// (comparison is bf16-grade: 2% rel + 8*bf16_eps floor).
// ws layout (needs 64 MB):
//   [0,8M)    Qb   bf16 [B,H,S,DK]  (post-PE)
//   [8M,24M)  Kf   fp32 [B,H,S,DK]  (raw K, pre-smear)
//   [24M,32M) Kb   bf16 [B,H,S,DK]  (post EMA+PE)
//   [32M,40M) Vb   bf16 [B,H,S,DK]
//   [40M,48M) Ab   bf16 [B,S,D]     (attention out)
//   [48M,64M) Yp   fp32 [B,S,D]     (out-proj + residual, pre-LN)

#define LB __launch_bounds__(256)

typedef unsigned short u16;
typedef __attribute__((ext_vector_type(4))) unsigned short us4;
typedef __attribute__((ext_vector_type(8))) unsigned short us8;
typedef __attribute__((ext_vector_type(8))) __bf16 bf8;
typedef __attribute__((ext_vector_type(4))) float f4;

static __device__ __forceinline__ float bf2f(u16 h) {
  union { unsigned int u; float f; } c; c.u = ((unsigned int)h) << 16; return c.f;
}
static __device__ __forceinline__ u16 f2bf(float f) {
  union { float f; unsigned int u; } c; c.f = f;
  unsigned int u = c.u + 0x7FFFu + ((c.u >> 16) & 1u);
  return (u16)(u >> 16);
}
// pe[s, dk]: i = dk/2, freq = 10000^(-2i/64); even->sin, odd->cos
static __device__ __forceinline__ float pe_val(int s, int dk) {
  float fr = __expf((float)(dk & ~1) * (-9.210340371976184f / 64.0f));
  float ang = (float)s * fr;
  return (dk & 1) ? __cosf(ang) : __sinf(ang);
}

// ---------------- QKV projection GEMM ----------------
__global__ LB void gemm_qkv(const float* __restrict__ X, const float* __restrict__ Wq,
                            const float* __restrict__ Wk, const float* __restrict__ Wv,
                            u16* __restrict__ Qb, float* __restrict__ Kf,
                            u16* __restrict__ Vb) {
  __shared__ u16 Als[128 * 40];
  __shared__ u16 Bls[128 * 40];
  const int tid = threadIdx.x;
  const int w = tid >> 6, lane = tid & 63;
  const int l16 = lane & 15, quad = lane >> 4;
  const int wm = w & 1, wn = w >> 1;
  const int m0 = blockIdx.y * 128, n0 = blockIdx.x * 128;
  const int z = blockIdx.z;
  const float* Wp = (z == 0) ? Wq : ((z == 1) ? Wk : Wv);

  f4 acc[4][4];
#pragma unroll
  for (int a = 0; a < 4; a++)
#pragma unroll
    for (int b = 0; b < 4; b++) acc[a][b] = f4{0.f, 0.f, 0.f, 0.f};

  for (int kk = 0; kk < 1024; kk += 32) {
    __syncthreads();
#pragma unroll
    for (int it = 0; it < 4; it++) {
      int c = tid + it * 256;
      int row = c >> 3, kc = c & 7;
      f4 va = *(const f4*)(X + (size_t)(m0 + row) * 1024 + kk + kc * 4);
      us4 pa = {f2bf(va[0]), f2bf(va[1]), f2bf(va[2]), f2bf(va[3])};
      *(us4*)(&Als[row * 40 + kc * 4]) = pa;
      f4 vb = *(const f4*)(Wp + (size_t)(n0 + row) * 1024 + kk + kc * 4);
      us4 pb = {f2bf(vb[0]), f2bf(vb[1]), f2bf(vb[2]), f2bf(vb[3])};
      *(us4*)(&Bls[row * 40 + kc * 4]) = pb;
    }
    __syncthreads();
    bf8 af[4], bfr[4];
#pragma unroll
    for (int mt = 0; mt < 4; mt++)
      af[mt] = __builtin_bit_cast(bf8, *(const us8*)(&Als[(wm * 64 + mt * 16 + l16) * 40 + quad * 8]));
#pragma unroll
    for (int nt = 0; nt < 4; nt++)
      bfr[nt] = __builtin_bit_cast(bf8, *(const us8*)(&Bls[(wn * 64 + nt * 16 + l16) * 40 + quad * 8]));
#pragma unroll
    for (int mt = 0; mt < 4; mt++)
#pragma unroll
      for (int nt = 0; nt < 4; nt++)
        acc[mt][nt] = __builtin_amdgcn_mfma_f32_16x16x32_bf16(af[mt], bfr[nt], acc[mt][nt], 0, 0, 0);
  }
#pragma unroll
  for (int mt = 0; mt < 4; mt++)
#pragma unroll
    for (int nt = 0; nt < 4; nt++)
#pragma unroll
      for (int r = 0; r < 4; r++) {
        int m = m0 + wm * 64 + mt * 16 + quad * 4 + r;
        int n = n0 + wn * 64 + nt * 16 + l16;
        float v = acc[mt][nt][r];
        int b = m >> 11, s = m & 2047, h = n >> 6, dk = n & 63;
        size_t o = (((size_t)(b * 16 + h)) * 2048 + s) * 64 + dk;  // [B,H,S,DK]
        if (z == 0)      Qb[o] = f2bf(v + pe_val(s, dk));
        else if (z == 1) Kf[o] = v;
        else             Vb[o] = f2bf(v);
      }
}

// ---------------- EMA smear + PE on K ----------------
__global__ LB void ema_pe(const float* __restrict__ Kf, const float* __restrict__ alpha,
                          u16* __restrict__ Kb) {
  int idx = blockIdx.x * 256 + threadIdx.x;
  int dk4 = (idx & 15) * 4;
  int s   = (idx >> 4) & 2047;
  int bh  = idx >> 15;
  size_t base = ((size_t)bh * 2048 + s) * 64 + dk4;
  f4 kc = *(const f4*)(Kf + base);
  f4 kv = kc;
  if (s > 0) {
    f4 kp = *(const f4*)(Kf + base - 64);
    float aa = alpha[(bh & 15) * 2047 + s - 1];
    float a = 1.0f / (1.0f + __expf(-aa));
#pragma unroll
    for (int j = 0; j < 4; j++) kv[j] = kc[j] * a + kp[j] * (1.0f - a);
  }
#pragma unroll
  for (int j = 0; j < 4; j++) Kb[base + j] = f2bf(kv[j] + pe_val(s, dk4 + j));
}

// ---------------- causal flash attention (no-running-max, 64-key steps) ----------------
// p = exp(s/8 - 32*ln2): fixed offset; scores bounded so no overflow, p>=2^-62
// floors far above fp32 denormal. l accumulated per-lane, reduced once at end.
// LDS rows stride 72 elems (144 B): 16B-aligned for b128, bank shift 4/row.
template<bool MASK>
static __device__ __forceinline__ void attn_step(
    int kt, size_t base, const u16* __restrict__ Kb, const u16* __restrict__ Vb,
    u16* vt, u16* Pw, const bf8* qa, f4* acc, float* lrow,
    int w, int lane, int l16, int quad, int thr) {
  // stage V tile (keys kt..kt+63) transposed into vt[d][key]
  const u16* vsrc = Vb + base + (size_t)(kt + lane) * 64 + w * 16;
  us8 v0 = *(const us8*)(vsrc);
  us8 v1 = *(const us8*)(vsrc + 8);
  char* vtb = (char*)vt + (w * 16) * 144 + lane * 2;
#pragma unroll
  for (int j = 0; j < 8; j++) *(u16*)(vtb + j * 144) = (u16)v0[j];
#pragma unroll
  for (int j = 0; j < 8; j++) *(u16*)(vtb + (8 + j) * 144) = (u16)v1[j];

  // QK^T: sc[t] covers keys kt+16t+l16, rows quad*4+r (wave-local)
  f4 sc[4];
#pragma unroll
  for (int t = 0; t < 4; t++) sc[t] = f4{0.f, 0.f, 0.f, 0.f};
#pragma unroll
  for (int t = 0; t < 4; t++)
#pragma unroll
    for (int c = 0; c < 2; c++) {
      bf8 kb = __builtin_bit_cast(bf8,
          *(const us8*)(Kb + base + (size_t)(kt + 16 * t + l16) * 64 + c * 32 + quad * 8));
      sc[t] = __builtin_amdgcn_mfma_f32_16x16x32_bf16(qa[c], kb, sc[t], 0, 0, 0);
    }
  // p = exp(s*0.125 - 22.18); accumulate l per-lane; P -> per-wave LDS (A-layout rows)
  char* pb = (char*)Pw + quad * 576 + l16 * 2;
#pragma unroll
  for (int r = 0; r < 4; r++)
#pragma unroll
    for (int t = 0; t < 4; t++) {
      float s = sc[t][r];
      if (MASK && (16 * t + l16 > thr + r)) s = -1e30f;
      float p = __expf(__builtin_fmaf(s, 0.125f, -22.18070977791825f));
      lrow[r] += p;
      __bf16 pbf = (__bf16)p;
      *(u16*)(pb + r * 144 + t * 32) = __builtin_bit_cast(u16, pbf);
    }
  __syncthreads();  // V tile staged by all waves (P is per-wave: lgkmcnt suffices)
  // PV: A = P[q=l16][k], B = Vt[d=dn*16+l16][k]
#pragma unroll
  for (int kk2 = 0; kk2 < 2; kk2++) {
    bf8 pa = __builtin_bit_cast(bf8, *(const us8*)((char*)Pw + l16 * 144 + kk2 * 64 + quad * 16));
#pragma unroll
    for (int dn = 0; dn < 4; dn++) {
      bf8 vb = __builtin_bit_cast(bf8,
          *(const us8*)((char*)vt + (dn * 16 + l16) * 144 + kk2 * 64 + quad * 16));
      acc[dn] = __builtin_amdgcn_mfma_f32_16x16x32_bf16(pa, vb, acc[dn], 0, 0, 0);
    }
  }
}

__global__ LB void attn_kernel(const u16* __restrict__ Qb, const u16* __restrict__ Kb,
                               const u16* __restrict__ Vb, u16* __restrict__ Ab) {
  __shared__ u16 Vt[2][64 * 72];   // double-buffered transposed V tile
  __shared__ u16 Pls[4][16 * 72];  // per-wave P
  const int tid = threadIdx.x, w = tid >> 6, lane = tid & 63;
  const int l16 = lane & 15, quad = lane >> 4;
  // heavy-first: first-dispatched blocks take the largest q0, spread over all bh
  const int idx = blockIdx.x;
  const int bh = idx & 31;
  const int q0 = (31 - (idx >> 5)) * 64;
  const size_t base = (size_t)bh * (2048 * 64);
  u16* Pw = Pls[w];

  bf8 qa[2];
  const int qrow = q0 + w * 16 + l16;
#pragma unroll
  for (int c = 0; c < 2; c++)
    qa[c] = __builtin_bit_cast(bf8, *(const us8*)(Qb + base + (size_t)qrow * 64 + c * 32 + quad * 8));

  f4 acc[4];
#pragma unroll
  for (int dn = 0; dn < 4; dn++) acc[dn] = f4{0.f, 0.f, 0.f, 0.f};
  float lrow[4] = {0.f, 0.f, 0.f, 0.f};
  const int thr = w * 16 + quad * 4;  // diag-tile mask threshold (row - q0 - r)

  int buf = 0;
  for (int kt = 0; kt < q0; kt += 64, buf ^= 1)
    attn_step<false>(kt, base, Kb, Vb, Vt[buf], Pw, qa, acc, lrow, w, lane, l16, quad, thr);
  attn_step<true>(q0, base, Kb, Vb, Vt[buf], Pw, qa, acc, lrow, w, lane, l16, quad, thr);

#pragma unroll
  for (int r = 0; r < 4; r++)
#pragma unroll
    for (int d = 1; d < 16; d <<= 1) lrow[r] += __shfl_xor(lrow[r], d, 64);

  const int b = bh >> 4, h = bh & 15;
#pragma unroll
  for (int dn = 0; dn < 4; dn++)
#pragma unroll
    for (int r = 0; r < 4; r++) {
      int q = q0 + w * 16 + quad * 4 + r;
      float v = acc[dn][r] / lrow[r];
      Ab[((size_t)(b * 2048 + q)) * 1024 + h * 64 + dn * 16 + l16] = f2bf(v);
    }
}

// ---------------- output projection + residual ----------------
__global__ LB void gemm_out(const u16* __restrict__ A, const float* __restrict__ Wo,
                            const float* __restrict__ X, float* __restrict__ Yp) {
  __shared__ u16 Als[128 * 40];
  __shared__ u16 Bls[128 * 40];
  const int tid = threadIdx.x;
  const int w = tid >> 6, lane = tid & 63;
  const int l16 = lane & 15, quad = lane >> 4;
  const int wm = w & 1, wn = w >> 1;
  const int m0 = blockIdx.y * 128, n0 = blockIdx.x * 128;

  f4 acc[4][4];
#pragma unroll
  for (int a = 0; a < 4; a++)
#pragma unroll
    for (int b = 0; b < 4; b++) acc[a][b] = f4{0.f, 0.f, 0.f, 0.f};

  for (int kk = 0; kk < 1024; kk += 32) {
    __syncthreads();
#pragma unroll
    for (int it = 0; it < 2; it++) {
      int c = tid + it * 256;
      int row = c >> 2, kc = c & 3;
      us8 va = *(const us8*)(A + (size_t)(m0 + row) * 1024 + kk + kc * 8);
      *(us8*)(&Als[row * 40 + kc * 8]) = va;
    }
#pragma unroll
    for (int it = 0; it < 4; it++) {
      int c = tid + it * 256;
      int row = c >> 3, kc = c & 7;
      f4 vb = *(const f4*)(Wo + (size_t)(n0 + row) * 1024 + kk + kc * 4);
      us4 pb = {f2bf(vb[0]), f2bf(vb[1]), f2bf(vb[2]), f2bf(vb[3])};
      *(us4*)(&Bls[row * 40 + kc * 4]) = pb;
    }
    __syncthreads();
    bf8 af[4], bfr[4];
#pragma unroll
    for (int mt = 0; mt < 4; mt++)
      af[mt] = __builtin_bit_cast(bf8, *(const us8*)(&Als[(wm * 64 + mt * 16 + l16) * 40 + quad * 8]));
#pragma unroll
    for (int nt = 0; nt < 4; nt++)
      bfr[nt] = __builtin_bit_cast(bf8, *(const us8*)(&Bls[(wn * 64 + nt * 16 + l16) * 40 + quad * 8]));
#pragma unroll
    for (int mt = 0; mt < 4; mt++)
#pragma unroll
      for (int nt = 0; nt < 4; nt++)
        acc[mt][nt] = __builtin_amdgcn_mfma_f32_16x16x32_bf16(af[mt], bfr[nt], acc[mt][nt], 0, 0, 0);
  }
#pragma unroll
  for (int mt = 0; mt < 4; mt++)
#pragma unroll
    for (int nt = 0; nt < 4; nt++)
#pragma unroll
      for (int r = 0; r < 4; r++) {
        int m = m0 + wm * 64 + mt * 16 + quad * 4 + r;
        int n = n0 + wn * 64 + nt * 16 + l16;
        size_t o = (size_t)m * 1024 + n;
        Yp[o] = acc[mt][nt][r] + X[o];
      }
}

// ---------------- LayerNorm ----------------
__global__ LB void ln_kernel(const float* __restrict__ Y, const float* __restrict__ g,
                             const float* __restrict__ bta, float* __restrict__ out) {
  __shared__ float ls[4], lsq[4];
  const int row = blockIdx.x, tid = threadIdx.x;
  const int w = tid >> 6, lane = tid & 63;
  f4 v = *(const f4*)(Y + (size_t)row * 1024 + tid * 4);
  float s  = v[0] + v[1] + v[2] + v[3];
  float sq = v[0] * v[0] + v[1] * v[1] + v[2] * v[2] + v[3] * v[3];
#pragma unroll
  for (int d = 1; d < 64; d <<= 1) { s += __shfl_xor(s, d, 64); sq += __shfl_xor(sq, d, 64); }
  if (lane == 0) { ls[w] = s; lsq[w] = sq; }
  __syncthreads();
  s  = ls[0] + ls[1] + ls[2] + ls[3];
  sq = lsq[0] + lsq[1] + lsq[2] + lsq[3];
  float mu  = s * (1.0f / 1024.0f);
  float var = sq * (1.0f / 1024.0f) - mu * mu;
  float rs  = rsqrtf(var + 1e-5f);
  f4 o;
#pragma unroll
  for (int j = 0; j < 4; j++) {
    int col = tid * 4 + j;
    o[j] = (v[j] - mu) * rs * g[col] + bta[col];
  }
  *(f4*)(out + (size_t)row * 1024 + tid * 4) = o;
}

extern "C" void kernel_launch(void* const* d_in, const int* in_sizes, int n_in,
                              void* d_out, int out_size, void* d_ws, size_t ws_size,
                              hipStream_t stream) {
  (void)in_sizes; (void)n_in; (void)out_size; (void)ws_size;
  const float* X  = (const float*)d_in[0];
  const float* Wq = (const float*)d_in[1];
  const float* Wk = (const float*)d_in[2];
  const float* Wv = (const float*)d_in[3];
  const float* Wo = (const float*)d_in[4];
  const float* al = (const float*)d_in[5];
  const float* g  = (const float*)d_in[6];
  const float* bt = (const float*)d_in[7];

  char* ws = (char*)d_ws;
  u16*   Qb = (u16*)(ws);
  float* Kf = (float*)(ws + ((size_t)8  << 20));
  u16*   Kb = (u16*)(ws + ((size_t)24 << 20));
  u16*   Vb = (u16*)(ws + ((size_t)32 << 20));
  u16*   Ab = (u16*)(ws + ((size_t)40 << 20));
  float* Yp = (float*)(ws + ((size_t)48 << 20));

  gemm_qkv<<<dim3(8, 32, 3), 256, 0, stream>>>(X, Wq, Wk, Wv, Qb, Kf, Vb);
  ema_pe<<<dim3(4096), 256, 0, stream>>>(Kf, al, Kb);
  attn_kernel<<<dim3(1024), 256, 0, stream>>>(Qb, Kb, Vb, Ab);
  gemm_out<<<dim3(8, 32), 256, 0, stream>>>(Ab, Wo, X, Yp);
  ln_kernel<<<dim3(4096), 256, 0, stream>>>(Yp, g, bt, (float*)d_out);
}

// Round 4
// 273.826 us; speedup vs baseline: 1.4100x; 1.1902x over previous
//
#include <hip/hip_runtime.h>

// Inputs/outputs fp32; internal compute bf16 MFMA (bf16-grade comparison).
// ws layout (64 MB):
//   [0,16M)   Yp    fp32 [B,S,D]    (out-proj + residual, pre-LN)
//   [16M,24M) Xb    bf16 [B*S, D]
//   [24M,30M) Wcat  bf16 [3072,1024] (Wq|Wk|Wv rows)
//   [30M,32M) Wob   bf16 [1024,1024]
//   [32M,40M) Qb    bf16 [B,H,S,DK] (post-PE)
//   [40M,48M) Kraw  bf16 (pre-smear)  -> reused as Ab bf16 [B,S,D] after ema_pe
//   [48M,56M) Kb    bf16 [B,H,S,DK] (post EMA+PE)
//   [56M,64M) Vb    bf16 [B,H,S,DK]

#define LB __launch_bounds__(256)

typedef unsigned short u16;
typedef __attribute__((ext_vector_type(4))) unsigned short us4;
typedef __attribute__((ext_vector_type(8))) unsigned short us8;
typedef __attribute__((ext_vector_type(8))) __bf16 bf8;
typedef __attribute__((ext_vector_type(4))) float f4;

static __device__ __forceinline__ float bf2f(u16 h) {
  union { unsigned int u; float f; } c; c.u = ((unsigned int)h) << 16; return c.f;
}
static __device__ __forceinline__ u16 f2bf(float f) {
  union { float f; unsigned int u; } c; c.f = f;
  unsigned int u = c.u + 0x7FFFu + ((c.u >> 16) & 1u);
  return (u16)(u >> 16);
}
static __device__ __forceinline__ float pe_val(int s, int dk) {
  float fr = __expf((float)(dk & ~1) * (-9.210340371976184f / 64.0f));
  float ang = (float)s * fr;
  return (dk & 1) ? __cosf(ang) : __sinf(ang);
}

// async global->LDS, 16B per lane; lptr is the wave-uniform base (HW adds lane*16)
#define GLDS(gp, lp) __builtin_amdgcn_global_load_lds( \
    (const __attribute__((address_space(1))) void*)(gp), \
    (__attribute__((address_space(3))) void*)(lp), 16, 0, 0)

// ---------------- fp32 -> bf16 conversion pre-pass ----------------
__global__ LB void cvt_kernel(const float* __restrict__ X, const float* __restrict__ Wq,
                              const float* __restrict__ Wk, const float* __restrict__ Wv,
                              const float* __restrict__ Wo, u16* __restrict__ Xb,
                              u16* __restrict__ Wcat, u16* __restrict__ Wob) {
  const unsigned t = blockIdx.x * 256 + threadIdx.x;  // 1M threads x 8 elems
  const float* src; u16* dst; size_t off;
  if (t < (512u << 10))      { src = X;  dst = Xb;                off = t; }
  else if (t < (640u << 10)) { src = Wq; dst = Wcat;              off = t - (512u << 10); }
  else if (t < (768u << 10)) { src = Wk; dst = Wcat + (1u << 20); off = t - (640u << 10); }
  else if (t < (896u << 10)) { src = Wv; dst = Wcat + (2u << 20); off = t - (768u << 10); }
  else                       { src = Wo; dst = Wob;               off = t - (896u << 10); }
  off *= 8;
  f4 a = *(const f4*)(src + off);
  f4 b = *(const f4*)(src + off + 4);
  us8 o = {f2bf(a[0]), f2bf(a[1]), f2bf(a[2]), f2bf(a[3]),
           f2bf(b[0]), f2bf(b[1]), f2bf(b[2]), f2bf(b[3])};
  *(us8*)(dst + off) = o;
}

// ---------------- m97-style GEMM core ----------------
// C[m,n] = sum_k A[m,k]*B[n,k]; 128x128 tile, BK=32, global_load_lds staging.
static __device__ __forceinline__ void gemm_core(
    const u16* __restrict__ Abase, const u16* __restrict__ Bbase,
    u16* Als, u16* Bls, int m0, int n0, int tid, f4 acc[4][4]) {
  const int w = tid >> 6, lane = tid & 63;
  const int l16 = lane & 15, quad = lane >> 4;
  const int wm = w & 1, wn = w >> 1;
  for (int kk = 0; kk < 1024; kk += 32) {
    __syncthreads();  // previous iteration's frag reads complete
#pragma unroll
    for (int it = 0; it < 2; it++) {
      int cb = (w * 2 + it) * 64;        // chunk base (wave-uniform)
      int c = cb + lane;                 // 16B chunk id: row = c>>2, kc = c&3
      int row = c >> 2, kc = c & 3;
      GLDS(Abase + (size_t)(m0 + row) * 1024 + kk + kc * 8, &Als[cb * 8]);
      GLDS(Bbase + (size_t)(n0 + row) * 1024 + kk + kc * 8, &Bls[cb * 8]);
    }
    __syncthreads();  // drains vmcnt -> tiles visible
    bf8 af[4], bfr[4];
#pragma unroll
    for (int mt = 0; mt < 4; mt++)
      af[mt] = __builtin_bit_cast(bf8, *(const us8*)(&Als[(wm * 64 + mt * 16 + l16) * 32 + quad * 8]));
#pragma unroll
    for (int nt = 0; nt < 4; nt++)
      bfr[nt] = __builtin_bit_cast(bf8, *(const us8*)(&Bls[(wn * 64 + nt * 16 + l16) * 32 + quad * 8]));
#pragma unroll
    for (int mt = 0; mt < 4; mt++)
#pragma unroll
      for (int nt = 0; nt < 4; nt++)
        acc[mt][nt] = __builtin_amdgcn_mfma_f32_16x16x32_bf16(af[mt], bfr[nt], acc[mt][nt], 0, 0, 0);
  }
}

// ---------------- QKV projection (fused N=3072) ----------------
__global__ LB void gemm_qkv(const u16* __restrict__ Xb, const u16* __restrict__ Wcat,
                            u16* __restrict__ Qb, u16* __restrict__ Kraw,
                            u16* __restrict__ Vb) {
  __shared__ u16 Als[128 * 32];
  __shared__ u16 Bls[128 * 32];
  const int tid = threadIdx.x;
  const int m0 = blockIdx.y * 128, n0 = blockIdx.x * 128;
  f4 acc[4][4];
#pragma unroll
  for (int a = 0; a < 4; a++)
#pragma unroll
    for (int b = 0; b < 4; b++) acc[a][b] = f4{0.f, 0.f, 0.f, 0.f};
  gemm_core(Xb, Wcat, Als, Bls, m0, n0, tid, acc);

  const int w = tid >> 6, lane = tid & 63;
  const int l16 = lane & 15, quad = lane >> 4;
  const int wm = w & 1, wn = w >> 1;
  const int z = blockIdx.x >> 3;  // 0:Q 1:K 2:V (block-uniform)
  u16* dst = (z == 0) ? Qb : ((z == 1) ? Kraw : Vb);
#pragma unroll
  for (int mt = 0; mt < 4; mt++)
#pragma unroll
    for (int nt = 0; nt < 4; nt++)
#pragma unroll
      for (int r = 0; r < 4; r++) {
        int m = m0 + wm * 64 + mt * 16 + quad * 4 + r;
        int nn = (n0 + wn * 64 + nt * 16 + l16) & 1023;
        float v = acc[mt][nt][r];
        int b = m >> 11, s = m & 2047, h = nn >> 6, dk = nn & 63;
        size_t o = (((size_t)(b * 16 + h)) * 2048 + s) * 64 + dk;  // [B,H,S,DK]
        if (z == 0) v += pe_val(s, dk);
        dst[o] = f2bf(v);
      }
}

// ---------------- EMA smear + PE on K (bf16 in/out) ----------------
__global__ LB void ema_pe(const u16* __restrict__ Kraw, const float* __restrict__ alpha,
                          u16* __restrict__ Kb) {
  int idx = blockIdx.x * 256 + threadIdx.x;  // 512K threads x 8 elems
  int dk8 = (idx & 7) * 8;
  int s   = (idx >> 3) & 2047;
  int bh  = idx >> 14;
  size_t base = ((size_t)bh * 2048 + s) * 64 + dk8;
  us8 kc = *(const us8*)(Kraw + base);
  float kv[8];
#pragma unroll
  for (int j = 0; j < 8; j++) kv[j] = bf2f(kc[j]);
  if (s > 0) {
    us8 kp = *(const us8*)(Kraw + base - 64);
    float aa = alpha[(bh & 15) * 2047 + s - 1];
    float a = 1.0f / (1.0f + __expf(-aa));
#pragma unroll
    for (int j = 0; j < 8; j++) kv[j] = kv[j] * a + bf2f(kp[j]) * (1.0f - a);
  }
  us8 o;
#pragma unroll
  for (int j = 0; j < 8; j++) o[j] = f2bf(kv[j] + pe_val(s, dk8 + j));
  *(us8*)(Kb + base) = o;
}

// ---------------- causal flash attention (no-running-max, 64-key steps) ----------------
template<bool MASK>
static __device__ __forceinline__ void attn_step(
    int kt, size_t base, const u16* __restrict__ Kb, const u16* __restrict__ Vb,
    u16* vt, u16* Pw, const bf8* qa, f4* acc, float* lrow,
    int w, int lane, int l16, int quad, int thr) {
  const u16* vsrc = Vb + base + (size_t)(kt + lane) * 64 + w * 16;
  us8 v0 = *(const us8*)(vsrc);
  us8 v1 = *(const us8*)(vsrc + 8);
  char* vtb = (char*)vt + (w * 16) * 144 + lane * 2;
#pragma unroll
  for (int j = 0; j < 8; j++) *(u16*)(vtb + j * 144) = (u16)v0[j];
#pragma unroll
  for (int j = 0; j < 8; j++) *(u16*)(vtb + (8 + j) * 144) = (u16)v1[j];

  f4 sc[4];
#pragma unroll
  for (int t = 0; t < 4; t++) sc[t] = f4{0.f, 0.f, 0.f, 0.f};
#pragma unroll
  for (int t = 0; t < 4; t++)
#pragma unroll
    for (int c = 0; c < 2; c++) {
      bf8 kb = __builtin_bit_cast(bf8,
          *(const us8*)(Kb + base + (size_t)(kt + 16 * t + l16) * 64 + c * 32 + quad * 8));
      sc[t] = __builtin_amdgcn_mfma_f32_16x16x32_bf16(qa[c], kb, sc[t], 0, 0, 0);
    }
  char* pb = (char*)Pw + quad * 576 + l16 * 2;
#pragma unroll
  for (int r = 0; r < 4; r++)
#pragma unroll
    for (int t = 0; t < 4; t++) {
      float s = sc[t][r];
      if (MASK && (16 * t + l16 > thr + r)) s = -1e30f;
      float p = __expf(__builtin_fmaf(s, 0.125f, -22.18070977791825f));
      lrow[r] += p;
      __bf16 pbf = (__bf16)p;
      *(u16*)(pb + r * 144 + t * 32) = __builtin_bit_cast(u16, pbf);
    }
  __syncthreads();
#pragma unroll
  for (int kk2 = 0; kk2 < 2; kk2++) {
    bf8 pa = __builtin_bit_cast(bf8, *(const us8*)((char*)Pw + l16 * 144 + kk2 * 64 + quad * 16));
#pragma unroll
    for (int dn = 0; dn < 4; dn++) {
      bf8 vb = __builtin_bit_cast(bf8,
          *(const us8*)((char*)vt + (dn * 16 + l16) * 144 + kk2 * 64 + quad * 16));
      acc[dn] = __builtin_amdgcn_mfma_f32_16x16x32_bf16(pa, vb, acc[dn], 0, 0, 0);
    }
  }
}

__global__ LB void attn_kernel(const u16* __restrict__ Qb, const u16* __restrict__ Kb,
                               const u16* __restrict__ Vb, u16* __restrict__ Ab) {
  __shared__ u16 Vt[2][64 * 72];
  __shared__ u16 Pls[4][16 * 72];
  const int tid = threadIdx.x, w = tid >> 6, lane = tid & 63;
  const int l16 = lane & 15, quad = lane >> 4;
  const int idx = blockIdx.x;
  const int bh = idx & 31;
  const int q0 = (31 - (idx >> 5)) * 64;  // heavy-first
  const size_t base = (size_t)bh * (2048 * 64);
  u16* Pw = Pls[w];

  bf8 qa[2];
  const int qrow = q0 + w * 16 + l16;
#pragma unroll
  for (int c = 0; c < 2; c++)
    qa[c] = __builtin_bit_cast(bf8, *(const us8*)(Qb + base + (size_t)qrow * 64 + c * 32 + quad * 8));

  f4 acc[4];
#pragma unroll
  for (int dn = 0; dn < 4; dn++) acc[dn] = f4{0.f, 0.f, 0.f, 0.f};
  float lrow[4] = {0.f, 0.f, 0.f, 0.f};
  const int thr = w * 16 + quad * 4;

  int buf = 0;
  for (int kt = 0; kt < q0; kt += 64, buf ^= 1)
    attn_step<false>(kt, base, Kb, Vb, Vt[buf], Pw, qa, acc, lrow, w, lane, l16, quad, thr);
  attn_step<true>(q0, base, Kb, Vb, Vt[buf], Pw, qa, acc, lrow, w, lane, l16, quad, thr);

#pragma unroll
  for (int r = 0; r < 4; r++)
#pragma unroll
    for (int d = 1; d < 16; d <<= 1) lrow[r] += __shfl_xor(lrow[r], d, 64);

  const int b = bh >> 4, h = bh & 15;
#pragma unroll
  for (int dn = 0; dn < 4; dn++)
#pragma unroll
    for (int r = 0; r < 4; r++) {
      int q = q0 + w * 16 + quad * 4 + r;
      float v = acc[dn][r] / lrow[r];
      Ab[((size_t)(b * 2048 + q)) * 1024 + h * 64 + dn * 16 + l16] = f2bf(v);
    }
}

// ---------------- output projection + residual ----------------
__global__ LB void gemm_out(const u16* __restrict__ Ab, const u16* __restrict__ Wob,
                            const float* __restrict__ X, float* __restrict__ Yp) {
  __shared__ u16 Als[128 * 32];
  __shared__ u16 Bls[128 * 32];
  const int tid = threadIdx.x;
  const int m0 = blockIdx.y * 128, n0 = blockIdx.x * 128;
  f4 acc[4][4];
#pragma unroll
  for (int a = 0; a < 4; a++)
#pragma unroll
    for (int b = 0; b < 4; b++) acc[a][b] = f4{0.f, 0.f, 0.f, 0.f};
  gemm_core(Ab, Wob, Als, Bls, m0, n0, tid, acc);

  const int w = tid >> 6, lane = tid & 63;
  const int l16 = lane & 15, quad = lane >> 4;
  const int wm = w & 1, wn = w >> 1;
#pragma unroll
  for (int mt = 0; mt < 4; mt++)
#pragma unroll
    for (int nt = 0; nt < 4; nt++)
#pragma unroll
      for (int r = 0; r < 4; r++) {
        int m = m0 + wm * 64 + mt * 16 + quad * 4 + r;
        int n = n0 + wn * 64 + nt * 16 + l16;
        size_t o = (size_t)m * 1024 + n;
        Yp[o] = acc[mt][nt][r] + X[o];
      }
}

// ---------------- LayerNorm ----------------
__global__ LB void ln_kernel(const float* __restrict__ Y, const float* __restrict__ g,
                             const float* __restrict__ bta, float* __restrict__ out) {
  __shared__ float ls[4], lsq[4];
  const int row = blockIdx.x, tid = threadIdx.x;
  const int w = tid >> 6, lane = tid & 63;
  f4 v = *(const f4*)(Y + (size_t)row * 1024 + tid * 4);
  float s  = v[0] + v[1] + v[2] + v[3];
  float sq = v[0] * v[0] + v[1] * v[1] + v[2] * v[2] + v[3] * v[3];
#pragma unroll
  for (int d = 1; d < 64; d <<= 1) { s += __shfl_xor(s, d, 64); sq += __shfl_xor(sq, d, 64); }
  if (lane == 0) { ls[w] = s; lsq[w] = sq; }
  __syncthreads();
  s  = ls[0] + ls[1] + ls[2] + ls[3];
  sq = lsq[0] + lsq[1] + lsq[2] + lsq[3];
  float mu  = s * (1.0f / 1024.0f);
  float var = sq * (1.0f / 1024.0f) - mu * mu;
  float rs  = rsqrtf(var + 1e-5f);
  f4 o;
#pragma unroll
  for (int j = 0; j < 4; j++) {
    int col = tid * 4 + j;
    o[j] = (v[j] - mu) * rs * g[col] + bta[col];
  }
  *(f4*)(out + (size_t)row * 1024 + tid * 4) = o;
}

extern "C" void kernel_launch(void* const* d_in, const int* in_sizes, int n_in,
                              void* d_out, int out_size, void* d_ws, size_t ws_size,
                              hipStream_t stream) {
  (void)in_sizes; (void)n_in; (void)out_size; (void)ws_size;
  const float* X  = (const float*)d_in[0];
  const float* Wq = (const float*)d_in[1];
  const float* Wk = (const float*)d_in[2];
  const float* Wv = (const float*)d_in[3];
  const float* Wo = (const float*)d_in[4];
  const float* al = (const float*)d_in[5];
  const float* g  = (const float*)d_in[6];
  const float* bt = (const float*)d_in[7];

  char* ws = (char*)d_ws;
  float* Yp   = (float*)(ws);
  u16*   Xb   = (u16*)(ws + ((size_t)16 << 20));
  u16*   Wcat = (u16*)(ws + ((size_t)24 << 20));
  u16*   Wob  = (u16*)(ws + ((size_t)30 << 20));
  u16*   Qb   = (u16*)(ws + ((size_t)32 << 20));
  u16*   Kraw = (u16*)(ws + ((size_t)40 << 20));
  u16*   Ab   = (u16*)(ws + ((size_t)40 << 20));  // reuses Kraw (dead after ema_pe)
  u16*   Kb   = (u16*)(ws + ((size_t)48 << 20));
  u16*   Vb   = (u16*)(ws + ((size_t)56 << 20));

  cvt_kernel<<<dim3(4096), 256, 0, stream>>>(X, Wq, Wk, Wv, Wo, Xb, Wcat, Wob);
  gemm_qkv<<<dim3(24, 32), 256, 0, stream>>>(Xb, Wcat, Qb, Kraw, Vb);
  ema_pe<<<dim3(2048), 256, 0, stream>>>(Kraw, al, Kb);
  attn_kernel<<<dim3(1024), 256, 0, stream>>>(Qb, Kb, Vb, Ab);
  gemm_out<<<dim3(8, 32), 256, 0, stream>>>(Ab, Wob, X, Yp);
  ln_kernel<<<dim3(4096), 256, 0, stream>>>(Yp, g, bt, (float*)d_out);
}

// Round 5
// 219.760 us; speedup vs baseline: 1.7569x; 1.2460x over previous
//
#include <hip/hip_runtime.h>

// Inputs/outputs fp32; internal compute bf16 MFMA (bf16-grade comparison).
// ws layout (64 MB):
//   [0,16M)   Yp    fp32 [B,S,D]
//   [16M,24M) Xb    bf16 [B*S, D]
//   [24M,30M) Wcat  bf16 [3072,1024]
//   [30M,32M) Wob   bf16 [1024,1024]
//   [32M,40M) Qb    bf16 [B,H,S,DK] (post-PE)
//   [40M,48M) Kraw  bf16 [B,H,S,DK] -> reused as Ab bf16 [B,S,D] after ema_pe
//   [48M,56M) Kp    bf16 packed K-frag order [bh][kt16][c][lane][j8]
//   [56M,64M) Vp    bf16 packed V^T-frag order [bh][kb64][t*4+dn][lane][j4]

#define LB __launch_bounds__(256)

typedef unsigned short u16;
typedef __attribute__((ext_vector_type(4))) unsigned short us4;
typedef __attribute__((ext_vector_type(8))) unsigned short us8;
typedef __attribute__((ext_vector_type(8))) __bf16 bf8;
typedef __attribute__((ext_vector_type(4))) float f4;
typedef __attribute__((ext_vector_type(4))) short s4;

static __device__ __forceinline__ float bf2f(u16 h) {
  union { unsigned int u; float f; } c; c.u = ((unsigned int)h) << 16; return c.f;
}
static __device__ __forceinline__ u16 f2bf(float f) {
  union { float f; unsigned int u; } c; c.f = f;
  unsigned int u = c.u + 0x7FFFu + ((c.u >> 16) & 1u);
  return (u16)(u >> 16);
}
static __device__ __forceinline__ float pe_val(int s, int dk) {
  float fr = __expf((float)(dk & ~1) * (-9.210340371976184f / 64.0f));
  float ang = (float)s * fr;
  return (dk & 1) ? __cosf(ang) : __sinf(ang);
}

// 16x16x16 bf16 MFMA, hedged across builtin generations.
#if __has_builtin(__builtin_amdgcn_mfma_f32_16x16x16bf16_1k)
static __device__ __forceinline__ f4 mfma16(us4 a, us4 b, f4 c) {
  return __builtin_amdgcn_mfma_f32_16x16x16bf16_1k(
      __builtin_bit_cast(s4, a), __builtin_bit_cast(s4, b), c, 0, 0, 0);
}
#elif __has_builtin(__builtin_amdgcn_mfma_f32_16x16x16_bf16)
typedef __attribute__((ext_vector_type(4))) __bf16 bf4;
static __device__ __forceinline__ f4 mfma16(us4 a, us4 b, f4 c) {
  return __builtin_amdgcn_mfma_f32_16x16x16_bf16(
      __builtin_bit_cast(bf4, a), __builtin_bit_cast(bf4, b), c, 0, 0, 0);
}
#else
static __device__ __forceinline__ f4 mfma16(us4 a, us4 b, f4 c) {
  asm volatile("v_mfma_f32_16x16x16_bf16 %0, %1, %2, %0" : "+v"(c) : "v"(a), "v"(b));
  return c;
}
#endif

#define GLDS(gp, lp) __builtin_amdgcn_global_load_lds( \
    (const __attribute__((address_space(1))) void*)(gp), \
    (__attribute__((address_space(3))) void*)(lp), 16, 0, 0)

// ---------------- fp32 -> bf16 conversion pre-pass ----------------
__global__ LB void cvt_kernel(const float* __restrict__ X, const float* __restrict__ Wq,
                              const float* __restrict__ Wk, const float* __restrict__ Wv,
                              const float* __restrict__ Wo, u16* __restrict__ Xb,
                              u16* __restrict__ Wcat, u16* __restrict__ Wob) {
  const unsigned t = blockIdx.x * 256 + threadIdx.x;
  const float* src; u16* dst; size_t off;
  if (t < (512u << 10))      { src = X;  dst = Xb;                off = t; }
  else if (t < (640u << 10)) { src = Wq; dst = Wcat;              off = t - (512u << 10); }
  else if (t < (768u << 10)) { src = Wk; dst = Wcat + (1u << 20); off = t - (640u << 10); }
  else if (t < (896u << 10)) { src = Wv; dst = Wcat + (2u << 20); off = t - (768u << 10); }
  else                       { src = Wo; dst = Wob;               off = t - (896u << 10); }
  off *= 8;
  f4 a = *(const f4*)(src + off);
  f4 b = *(const f4*)(src + off + 4);
  us8 o = {f2bf(a[0]), f2bf(a[1]), f2bf(a[2]), f2bf(a[3]),
           f2bf(b[0]), f2bf(b[1]), f2bf(b[2]), f2bf(b[3])};
  *(us8*)(dst + off) = o;
}

// ---------------- m97-style GEMM core ----------------
static __device__ __forceinline__ void gemm_core(
    const u16* __restrict__ Abase, const u16* __restrict__ Bbase,
    u16* Als, u16* Bls, int m0, int n0, int tid, f4 acc[4][4]) {
  const int w = tid >> 6, lane = tid & 63;
  const int l16 = lane & 15, quad = lane >> 4;
  const int wm = w & 1, wn = w >> 1;
  for (int kk = 0; kk < 1024; kk += 32) {
    __syncthreads();
#pragma unroll
    for (int it = 0; it < 2; it++) {
      int cb = (w * 2 + it) * 64;
      int c = cb + lane;
      int row = c >> 2, kc = c & 3;
      GLDS(Abase + (size_t)(m0 + row) * 1024 + kk + kc * 8, &Als[cb * 8]);
      GLDS(Bbase + (size_t)(n0 + row) * 1024 + kk + kc * 8, &Bls[cb * 8]);
    }
    __syncthreads();
    bf8 af[4], bfr[4];
#pragma unroll
    for (int mt = 0; mt < 4; mt++)
      af[mt] = __builtin_bit_cast(bf8, *(const us8*)(&Als[(wm * 64 + mt * 16 + l16) * 32 + quad * 8]));
#pragma unroll
    for (int nt = 0; nt < 4; nt++)
      bfr[nt] = __builtin_bit_cast(bf8, *(const us8*)(&Bls[(wn * 64 + nt * 16 + l16) * 32 + quad * 8]));
#pragma unroll
    for (int mt = 0; mt < 4; mt++)
#pragma unroll
      for (int nt = 0; nt < 4; nt++)
        acc[mt][nt] = __builtin_amdgcn_mfma_f32_16x16x32_bf16(af[mt], bfr[nt], acc[mt][nt], 0, 0, 0);
  }
}

// ---------------- QKV projection (fused N=3072) ----------------
__global__ LB void gemm_qkv(const u16* __restrict__ Xb, const u16* __restrict__ Wcat,
                            u16* __restrict__ Qb, u16* __restrict__ Kraw,
                            u16* __restrict__ Vp) {
  __shared__ u16 Als[128 * 32];
  __shared__ u16 Bls[128 * 32];
  const int tid = threadIdx.x;
  const int m0 = blockIdx.y * 128, n0 = blockIdx.x * 128;
  f4 acc[4][4];
#pragma unroll
  for (int a = 0; a < 4; a++)
#pragma unroll
    for (int b = 0; b < 4; b++) acc[a][b] = f4{0.f, 0.f, 0.f, 0.f};
  gemm_core(Xb, Wcat, Als, Bls, m0, n0, tid, acc);

  const int w = tid >> 6, lane = tid & 63;
  const int l16 = lane & 15, quad = lane >> 4;
  const int wm = w & 1, wn = w >> 1;
  const int z = blockIdx.x >> 3;  // 0:Q 1:K 2:V
#pragma unroll
  for (int mt = 0; mt < 4; mt++)
#pragma unroll
    for (int nt = 0; nt < 4; nt++)
#pragma unroll
      for (int r = 0; r < 4; r++) {
        int m = m0 + wm * 64 + mt * 16 + quad * 4 + r;
        int nn = (n0 + wn * 64 + nt * 16 + l16) & 1023;
        float v = acc[mt][nt][r];
        int b = m >> 11, s = m & 2047, h = nn >> 6, dk = nn & 63;
        size_t bhoff = (size_t)(b * 16 + h) * (2048 * 64);
        if (z == 0) {
          Qb[bhoff + (size_t)s * 64 + dk] = f2bf(v + pe_val(s, dk));
        } else if (z == 1) {
          Kraw[bhoff + (size_t)s * 64 + dk] = f2bf(v);
        } else {
          // packed V^T-frag order: [kb64][(t*4+dn)][Q*16+l16 (=lane)][j]
          int kb = s >> 6, sl = s & 63;
          int t = sl >> 4, Qq = (sl >> 2) & 3, jj = sl & 3;
          int dn = dk >> 4, lv = dk & 15;
          Vp[bhoff + (size_t)kb * 4096 + ((t * 4 + dn) * 64 + Qq * 16 + lv) * 4 + jj] = f2bf(v);
        }
      }
}

// ---------------- EMA smear + PE on K; writes packed K-frag order ----------------
__global__ LB void ema_pe(const u16* __restrict__ Kraw, const float* __restrict__ alpha,
                          u16* __restrict__ Kp) {
  int idx = blockIdx.x * 256 + threadIdx.x;  // 512K threads x 8 elems
  int b8  = idx & 7;          // dk block: dk = b8*8..b8*8+7
  int s   = (idx >> 3) & 2047;
  int bh  = idx >> 14;
  int dk8 = b8 * 8;
  size_t base = ((size_t)bh * 2048 + s) * 64 + dk8;
  us8 kc = *(const us8*)(Kraw + base);
  float kv[8];
#pragma unroll
  for (int j = 0; j < 8; j++) kv[j] = bf2f(kc[j]);
  if (s > 0) {
    us8 kp = *(const us8*)(Kraw + base - 64);
    float aa = alpha[(bh & 15) * 2047 + s - 1];
    float a = 1.0f / (1.0f + __expf(-aa));
#pragma unroll
    for (int j = 0; j < 8; j++) kv[j] = kv[j] * a + bf2f(kp[j]) * (1.0f - a);
  }
  us8 o;
#pragma unroll
  for (int j = 0; j < 8; j++) o[j] = f2bf(kv[j] + pe_val(s, dk8 + j));
  // packed: [kt16][c][quad][l16][j8]; c=b8>>2, quad=b8&3, l16=s&15
  int kt16 = s >> 4, c = b8 >> 2, quad = b8 & 3, l16s = s & 15;
  size_t off = (size_t)bh * (2048 * 64) + (size_t)kt16 * 1024 + (c * 64 + quad * 16 + l16s) * 8;
  *(us8*)(Kp + off) = o;
}

// ---------------- causal attention: barrier-free, LDS-free ----------------
// Per wave: 16 q-rows (q = qw + l16). S^T = K·Q^T (x32 MFMA); softmax with fixed
// exp offset; P^T stays in registers as the 16x16x16 B-operand; O^T = V^T·P^T.
template<bool MASK>
static __device__ __forceinline__ void attn_step(
    int kb, const u16* __restrict__ Kt, const u16* __restrict__ Vt,
    const bf8* qf, f4* acc, float& lsum, int lane, int quad, int qrel0) {
  const u16* kbase = Kt + (size_t)kb * 4096;
  const u16* vbase = Vt + (size_t)kb * 4096;
  f4 sc[4];
#pragma unroll
  for (int t = 0; t < 4; t++) sc[t] = f4{0.f, 0.f, 0.f, 0.f};
#pragma unroll
  for (int t = 0; t < 4; t++)
#pragma unroll
    for (int c = 0; c < 2; c++) {
      bf8 kf = __builtin_bit_cast(bf8, *(const us8*)(kbase + (t * 2 + c) * 512 + lane * 8));
      sc[t] = __builtin_amdgcn_mfma_f32_16x16x32_bf16(kf, qf[c], sc[t], 0, 0, 0);
    }
  us4 pf[4];
#pragma unroll
  for (int t = 0; t < 4; t++) {
#pragma unroll
    for (int r = 0; r < 4; r++) {
      float s = sc[t][r];
      if (MASK && (t * 16 + quad * 4 + r > qrel0)) s = -1e30f;
      float p = __expf(__builtin_fmaf(s, 0.125f, -22.18070977791825f));
      lsum += p;
      pf[t][r] = f2bf(p);
    }
#pragma unroll
    for (int dn = 0; dn < 4; dn++) {
      us4 vf = *(const us4*)(vbase + ((t * 4 + dn) * 64 + lane) * 4);
      acc[dn] = mfma16(vf, pf[t], acc[dn]);
    }
  }
}

__global__ LB void attn_kernel(const u16* __restrict__ Qb, const u16* __restrict__ Kp,
                               const u16* __restrict__ Vp, u16* __restrict__ Ab) {
  const int tid = threadIdx.x, w = tid >> 6, lane = tid & 63;
  const int l16 = lane & 15, quad = lane >> 4;
  const int idx = blockIdx.x;
  const int bh = idx & 31;
  const int q0 = (31 - (idx >> 5)) * 64;  // heavy-first
  const int qw = q0 + w * 16;             // this wave's q-tile
  const size_t bhoff = (size_t)bh * (2048 * 64);
  const u16* Kt = Kp + bhoff;
  const u16* Vt = Vp + bhoff;

  bf8 qf[2];
#pragma unroll
  for (int c = 0; c < 2; c++)
    qf[c] = __builtin_bit_cast(bf8, *(const us8*)(Qb + bhoff + (size_t)(qw + l16) * 64 + c * 32 + quad * 8));

  f4 acc[4];
#pragma unroll
  for (int dn = 0; dn < 4; dn++) acc[dn] = f4{0.f, 0.f, 0.f, 0.f};
  float lsum = 0.f;

  const int nfull = (qw + 1) >> 6;
  for (int kb = 0; kb < nfull; kb++)
    attn_step<false>(kb, Kt, Vt, qf, acc, lsum, lane, quad, 0);
  attn_step<true>(nfull, Kt, Vt, qf, acc, lsum, lane, quad, qw + l16 - nfull * 64);

  lsum += __shfl_xor(lsum, 16, 64);
  lsum += __shfl_xor(lsum, 32, 64);
  float rinv = 1.0f / lsum;

  const int b = bh >> 4, h = bh & 15;
  const int q = qw + l16;
  u16* orow = Ab + ((size_t)(b * 2048 + q)) * 1024 + h * 64;
#pragma unroll
  for (int dn = 0; dn < 4; dn++) {
    us4 o = {f2bf(acc[dn][0] * rinv), f2bf(acc[dn][1] * rinv),
             f2bf(acc[dn][2] * rinv), f2bf(acc[dn][3] * rinv)};
    *(us4*)(orow + dn * 16 + quad * 4) = o;
  }
}

// ---------------- output projection + residual ----------------
__global__ LB void gemm_out(const u16* __restrict__ Ab, const u16* __restrict__ Wob,
                            const float* __restrict__ X, float* __restrict__ Yp) {
  __shared__ u16 Als[128 * 32];
  __shared__ u16 Bls[128 * 32];
  const int tid = threadIdx.x;
  const int m0 = blockIdx.y * 128, n0 = blockIdx.x * 128;
  f4 acc[4][4];
#pragma unroll
  for (int a = 0; a < 4; a++)
#pragma unroll
    for (int b = 0; b < 4; b++) acc[a][b] = f4{0.f, 0.f, 0.f, 0.f};
  gemm_core(Ab, Wob, Als, Bls, m0, n0, tid, acc);

  const int w = tid >> 6, lane = tid & 63;
  const int l16 = lane & 15, quad = lane >> 4;
  const int wm = w & 1, wn = w >> 1;
#pragma unroll
  for (int mt = 0; mt < 4; mt++)
#pragma unroll
    for (int nt = 0; nt < 4; nt++)
#pragma unroll
      for (int r = 0; r < 4; r++) {
        int m = m0 + wm * 64 + mt * 16 + quad * 4 + r;
        int n = n0 + wn * 64 + nt * 16 + l16;
        size_t o = (size_t)m * 1024 + n;
        Yp[o] = acc[mt][nt][r] + X[o];
      }
}

// ---------------- LayerNorm ----------------
__global__ LB void ln_kernel(const float* __restrict__ Y, const float* __restrict__ g,
                             const float* __restrict__ bta, float* __restrict__ out) {
  __shared__ float ls[4], lsq[4];
  const int row = blockIdx.x, tid = threadIdx.x;
  const int w = tid >> 6, lane = tid & 63;
  f4 v = *(const f4*)(Y + (size_t)row * 1024 + tid * 4);
  float s  = v[0] + v[1] + v[2] + v[3];
  float sq = v[0] * v[0] + v[1] * v[1] + v[2] * v[2] + v[3] * v[3];
#pragma unroll
  for (int d = 1; d < 64; d <<= 1) { s += __shfl_xor(s, d, 64); sq += __shfl_xor(sq, d, 64); }
  if (lane == 0) { ls[w] = s; lsq[w] = sq; }
  __syncthreads();
  s  = ls[0] + ls[1] + ls[2] + ls[3];
  sq = lsq[0] + lsq[1] + lsq[2] + lsq[3];
  float mu  = s * (1.0f / 1024.0f);
  float var = sq * (1.0f / 1024.0f) - mu * mu;
  float rs  = rsqrtf(var + 1e-5f);
  f4 o;
#pragma unroll
  for (int j = 0; j < 4; j++) {
    int col = tid * 4 + j;
    o[j] = (v[j] - mu) * rs * g[col] + bta[col];
  }
  *(f4*)(out + (size_t)row * 1024 + tid * 4) = o;
}

extern "C" void kernel_launch(void* const* d_in, const int* in_sizes, int n_in,
                              void* d_out, int out_size, void* d_ws, size_t ws_size,
                              hipStream_t stream) {
  (void)in_sizes; (void)n_in; (void)out_size; (void)ws_size;
  const float* X  = (const float*)d_in[0];
  const float* Wq = (const float*)d_in[1];
  const float* Wk = (const float*)d_in[2];
  const float* Wv = (const float*)d_in[3];
  const float* Wo = (const float*)d_in[4];
  const float* al = (const float*)d_in[5];
  const float* g  = (const float*)d_in[6];
  const float* bt = (const float*)d_in[7];

  char* ws = (char*)d_ws;
  float* Yp   = (float*)(ws);
  u16*   Xb   = (u16*)(ws + ((size_t)16 << 20));
  u16*   Wcat = (u16*)(ws + ((size_t)24 << 20));
  u16*   Wob  = (u16*)(ws + ((size_t)30 << 20));
  u16*   Qb   = (u16*)(ws + ((size_t)32 << 20));
  u16*   Kraw = (u16*)(ws + ((size_t)40 << 20));
  u16*   Ab   = (u16*)(ws + ((size_t)40 << 20));  // reuses Kraw
  u16*   Kp   = (u16*)(ws + ((size_t)48 << 20));
  u16*   Vp   = (u16*)(ws + ((size_t)56 << 20));

  cvt_kernel<<<dim3(4096), 256, 0, stream>>>(X, Wq, Wk, Wv, Wo, Xb, Wcat, Wob);
  gemm_qkv<<<dim3(24, 32), 256, 0, stream>>>(Xb, Wcat, Qb, Kraw, Vp);
  ema_pe<<<dim3(2048), 256, 0, stream>>>(Kraw, al, Kp);
  attn_kernel<<<dim3(1024), 256, 0, stream>>>(Qb, Kp, Vp, Ab);
  gemm_out<<<dim3(8, 32), 256, 0, stream>>>(Ab, Wob, X, Yp);
  ln_kernel<<<dim3(4096), 256, 0, stream>>>(Yp, g, bt, (float*)d_out);
}